// Round 1
// baseline (311.458 us; speedup 1.0000x reference)
//
#include <hip/hip_runtime.h>

// ---------------------------------------------------------------------------
// MultiHeadAttention: y = softmax((xWq^T)(xWk^T)^T / sqrt(dk)) (xWv^T) Wo^T + b
// B=2, S=4096, D=512, H=8, dk=64.  bf16 MFMA pipeline:
//   1) gemm_proj<f32A,QK>  : Q = q@Wq^T+bq  -> ws [B,H,S,64] bf16
//   2) gemm_proj<f32A,QK>  : K               -> ws [B,H,S,64] bf16
//   3) gemm_proj<f32A,VT>  : V               -> ws [B,H,64,S] bf16 (transposed)
//   4) attn_kernel         : flash attention -> ws Ctx [B*S, 512] bf16
//   5) gemm_proj<bf16A,F32>: out = Ctx@Wo^T+bo -> d_out fp32
// ---------------------------------------------------------------------------

#define DM   512
#define NH   8
#define DK   64
#define SEQ  4096
#define BATCH 2
#define MROWS (BATCH*SEQ)          // 8192

typedef __attribute__((ext_vector_type(4))) float  f32x4;
typedef __attribute__((ext_vector_type(8))) short  s16x8;   // 8 bf16 (4 VGPRs)
typedef __attribute__((ext_vector_type(4))) short  s16x4;
typedef __attribute__((ext_vector_type(4))) unsigned short u16x4;

static __device__ __forceinline__ unsigned short f2bf(float f) {
    union { float f; unsigned int u; } a; a.f = f;
    unsigned int r = a.u + 0x7FFFu + ((a.u >> 16) & 1u);   // RNE
    return (unsigned short)(r >> 16);
}

// ---------------------------------------------------------------------------
// GEMM: C[m,n] = sum_k A[m,k] * W[n,k] + bias[n]     (A: MROWSxDM, W: DMxDM)
// 128x128 tile, BK=32, 4 waves (2x2), each wave 64x64 via 4x4 16x16x32 MFMA.
// LDS rows padded to 40 bf16 (80 B) -> uniform bank load on ds_read_b128.
// OUT_MODE: 0 = bf16 [B,H,S,64], 1 = bf16 [B,H,64,S] (transposed), 2 = fp32 [M,DM]
// ---------------------------------------------------------------------------
template<bool A_BF16, int OUT_MODE>
__global__ __launch_bounds__(256)
void gemm_proj(const void* __restrict__ Aptr,
               const float* __restrict__ W,
               const float* __restrict__ bias,
               void* __restrict__ outp)
{
    __shared__ short As[128 * 40];
    __shared__ short Bs[128 * 40];

    const int tid  = threadIdx.x;
    const int lane = tid & 63;
    const int wid  = tid >> 6;
    const int g = lane >> 4, r = lane & 15;
    const int wm = wid >> 1, wn = wid & 1;
    const int brow = blockIdx.x * 128;
    const int bcol = blockIdx.y * 128;

    f32x4 acc[4][4];
    #pragma unroll
    for (int i = 0; i < 4; ++i)
        #pragma unroll
        for (int j = 0; j < 4; ++j) acc[i][j] = (f32x4)(0.0f);

    for (int k0 = 0; k0 < DM; k0 += 32) {
        // ---- stage A tile (128x32) ----
        if (A_BF16) {
            const short* A = (const short*)Aptr;
            #pragma unroll
            for (int j = 0; j < 2; ++j) {
                int c = tid + 256 * j;            // 512 chunks of 8 bf16
                int row = c >> 2, cc = c & 3;
                s16x8 v = *(const s16x8*)(A + (size_t)(brow + row) * DM + k0 + cc * 8);
                *(s16x8*)(&As[row * 40 + cc * 8]) = v;
            }
        } else {
            const float* A = (const float*)Aptr;
            #pragma unroll
            for (int j = 0; j < 4; ++j) {
                int c = tid + 256 * j;            // 1024 chunks of 4 f32
                int row = c >> 3, cc = c & 7;
                f32x4 v = *(const f32x4*)(A + (size_t)(brow + row) * DM + k0 + cc * 4);
                s16x4 b;
                b[0] = (short)f2bf(v[0]); b[1] = (short)f2bf(v[1]);
                b[2] = (short)f2bf(v[2]); b[3] = (short)f2bf(v[3]);
                *(s16x4*)(&As[row * 40 + cc * 4]) = b;
            }
        }
        // ---- stage W tile (128x32), fp32 -> bf16 ----
        #pragma unroll
        for (int j = 0; j < 4; ++j) {
            int c = tid + 256 * j;
            int row = c >> 3, cc = c & 7;
            f32x4 v = *(const f32x4*)(W + (size_t)(bcol + row) * DM + k0 + cc * 4);
            s16x4 b;
            b[0] = (short)f2bf(v[0]); b[1] = (short)f2bf(v[1]);
            b[2] = (short)f2bf(v[2]); b[3] = (short)f2bf(v[3]);
            *(s16x4*)(&Bs[row * 40 + cc * 4]) = b;
        }
        __syncthreads();

        s16x8 af[4], bfr[4];
        #pragma unroll
        for (int mf = 0; mf < 4; ++mf)
            af[mf] = *(const s16x8*)(&As[(wm * 64 + mf * 16 + r) * 40 + g * 8]);
        #pragma unroll
        for (int nf = 0; nf < 4; ++nf)
            bfr[nf] = *(const s16x8*)(&Bs[(wn * 64 + nf * 16 + r) * 40 + g * 8]);
        #pragma unroll
        for (int mf = 0; mf < 4; ++mf)
            #pragma unroll
            for (int nf = 0; nf < 4; ++nf)
                acc[mf][nf] = __builtin_amdgcn_mfma_f32_16x16x32_bf16(
                    af[mf], bfr[nf], acc[mf][nf], 0, 0, 0);
        __syncthreads();
    }

    // ---- epilogue ----
    const int ncolbase = bcol + wn * 64;
    const int mrowbase = brow + wm * 64;
    #pragma unroll
    for (int mf = 0; mf < 4; ++mf) {
        #pragma unroll
        for (int nf = 0; nf < 4; ++nf) {
            const int ncol = ncolbase + nf * 16 + r;
            const int m0   = mrowbase + mf * 16 + g * 4;
            const float bv = bias[ncol];
            if (OUT_MODE == 2) {
                float* O = (float*)outp;
                #pragma unroll
                for (int i = 0; i < 4; ++i)
                    O[(size_t)(m0 + i) * DM + ncol] = acc[mf][nf][i] + bv;
            } else if (OUT_MODE == 0) {
                unsigned short* O = (unsigned short*)outp;
                const int h = ncol >> 6, d = ncol & 63;
                #pragma unroll
                for (int i = 0; i < 4; ++i) {
                    int m = m0 + i;
                    int b = m >> 12, s = m & (SEQ - 1);
                    O[((size_t)(b * NH + h) * SEQ + s) * DK + d] =
                        f2bf(acc[mf][nf][i] + bv);
                }
            } else {
                unsigned short* O = (unsigned short*)outp;
                const int h = ncol >> 6, d = ncol & 63;
                const int b = m0 >> 12, s0 = m0 & (SEQ - 1);
                u16x4 pk;
                #pragma unroll
                for (int i = 0; i < 4; ++i) pk[i] = f2bf(acc[mf][nf][i] + bv);
                *(u16x4*)(&O[((size_t)(b * NH + h) * DK + d) * SEQ + s0]) = pk;
            }
        }
    }
}

// ---------------------------------------------------------------------------
// Flash attention, swapped orientation.
//   S^T  = mfma(A=K[t,d], B=Q[q,d])   -> C[t,q]: col(lane&15)=q, row=t
//   ctx^T= mfma(A=Vt[d,t], B=P[q,t])  -> C[d,q]: col(lane&15)=q, row=d
// Softmax stats (m,l) and rescale all live on lane&15 = q -> no stat shuffles
// beyond the 2-op (xor16/xor32) tile reduction.
// 4 waves x 64 q-rows, KV tile = 64. P goes through padded per-wave LDS to
// reach B-fragment layout. T14: next KV tile's global loads issued pre-compute.
// ---------------------------------------------------------------------------
#define CSC 0.18033688011112042f   // log2(e)/sqrt(64)

__global__ __launch_bounds__(256)
void attn_kernel(const unsigned short* __restrict__ Qw,
                 const unsigned short* __restrict__ Kw,
                 const unsigned short* __restrict__ Vtw,
                 unsigned short* __restrict__ Ctx)
{
    __shared__ short Ks[64 * 72];
    __shared__ short Vs[64 * 72];
    __shared__ short Ps[4 * 64 * 72];

    const int tid  = threadIdx.x;
    const int lane = tid & 63;
    const int wid  = tid >> 6;
    const int g = lane >> 4, r = lane & 15;
    const int qt = blockIdx.x;           // 0..15
    const int bh = blockIdx.y;           // 0..15  (= b*8 + h)
    const int q0 = qt * 256 + wid * 64;
    const size_t base = (size_t)bh * SEQ * DK;   // same offset for Kw and Vtw

    // Q resident as B-fragments: lane holds Q[q0+qf*16+r][df*32+g*8 .. +8]
    s16x8 qfr[4][2];
    #pragma unroll
    for (int qf = 0; qf < 4; ++qf)
        #pragma unroll
        for (int df = 0; df < 2; ++df)
            qfr[qf][df] = *(const s16x8*)((const short*)Qw + base +
                           (size_t)(q0 + qf * 16 + r) * DK + df * 32 + g * 8);

    float mrun[4], lrun[4];
    #pragma unroll
    for (int qf = 0; qf < 4; ++qf) { mrun[qf] = -1e30f; lrun[qf] = 0.0f; }
    f32x4 o[4][4];                        // o[df][qf] : ctx^T accumulator
    #pragma unroll
    for (int df = 0; df < 4; ++df)
        #pragma unroll
        for (int qf = 0; qf < 4; ++qf) o[df][qf] = (f32x4)(0.0f);

    short* Pw = &Ps[wid * (64 * 72)];

    // prologue load of KV tile 0
    s16x8 kr[2], vr[2];
    #pragma unroll
    for (int j = 0; j < 2; ++j) {
        int ch = tid + 256 * j;          // 512 chunks of 8 bf16
        int row = ch >> 3, cc = ch & 7;
        kr[j] = *(const s16x8*)((const short*)Kw  + base + (size_t)row * DK + cc * 8);
        vr[j] = *(const s16x8*)((const short*)Vtw + base + (size_t)row * SEQ + cc * 8);
    }

    for (int t0 = 0; t0 < SEQ; t0 += 64) {
        __syncthreads();                 // prior compute done reading Ks/Vs
        #pragma unroll
        for (int j = 0; j < 2; ++j) {
            int ch = tid + 256 * j;
            int row = ch >> 3, cc = ch & 7;
            *(s16x8*)(&Ks[row * 72 + cc * 8]) = kr[j];
            *(s16x8*)(&Vs[row * 72 + cc * 8]) = vr[j];
        }
        __syncthreads();
        if (t0 + 64 < SEQ) {             // T14: issue next tile's loads early
            #pragma unroll
            for (int j = 0; j < 2; ++j) {
                int ch = tid + 256 * j;
                int row = ch >> 3, cc = ch & 7;
                kr[j] = *(const s16x8*)((const short*)Kw  + base +
                         (size_t)(t0 + 64 + row) * DK + cc * 8);
                vr[j] = *(const s16x8*)((const short*)Vtw + base +
                         (size_t)row * SEQ + (t0 + 64) + cc * 8);
            }
        }

        // ---- S^T = K . Q^T ----
        f32x4 s[4][4];
        #pragma unroll
        for (int tf = 0; tf < 4; ++tf)
            #pragma unroll
            for (int qf = 0; qf < 4; ++qf) s[tf][qf] = (f32x4)(0.0f);
        #pragma unroll
        for (int tf = 0; tf < 4; ++tf) {
            s16x8 ka0 = *(const s16x8*)(&Ks[(tf * 16 + r) * 72 + g * 8]);
            s16x8 ka1 = *(const s16x8*)(&Ks[(tf * 16 + r) * 72 + 32 + g * 8]);
            #pragma unroll
            for (int qf = 0; qf < 4; ++qf) {
                s[tf][qf] = __builtin_amdgcn_mfma_f32_16x16x32_bf16(ka0, qfr[qf][0], s[tf][qf], 0, 0, 0);
                s[tf][qf] = __builtin_amdgcn_mfma_f32_16x16x32_bf16(ka1, qfr[qf][1], s[tf][qf], 0, 0, 0);
            }
        }

        // ---- online softmax along t (rows) per q (col = lane&15) ----
        #pragma unroll
        for (int qf = 0; qf < 4; ++qf) {
            float mx = -1e30f;
            #pragma unroll
            for (int tf = 0; tf < 4; ++tf)
                #pragma unroll
                for (int i = 0; i < 4; ++i) mx = fmaxf(mx, s[tf][qf][i]);
            mx = fmaxf(mx, __shfl_xor(mx, 16));
            mx = fmaxf(mx, __shfl_xor(mx, 32));
            float mnew = fmaxf(mrun[qf], mx);
            float al = exp2f((mrun[qf] - mnew) * CSC);
            mrun[qf] = mnew;
            float rs = 0.0f;
            #pragma unroll
            for (int tf = 0; tf < 4; ++tf)
                #pragma unroll
                for (int i = 0; i < 4; ++i) {
                    float p = exp2f((s[tf][qf][i] - mnew) * CSC);
                    s[tf][qf][i] = p;
                    rs += p;
                }
            rs += __shfl_xor(rs, 16);
            rs += __shfl_xor(rs, 32);
            lrun[qf] = lrun[qf] * al + rs;
            #pragma unroll
            for (int df = 0; df < 4; ++df) o[df][qf] *= al;
        }

        // ---- P -> bf16 -> per-wave LDS [q][t] (padded 72) ----
        #pragma unroll
        for (int qf = 0; qf < 4; ++qf)
            #pragma unroll
            for (int tf = 0; tf < 4; ++tf) {
                u16x4 pk;
                #pragma unroll
                for (int i = 0; i < 4; ++i) pk[i] = f2bf(s[tf][qf][i]);
                *(u16x4*)(&Pw[(qf * 16 + r) * 72 + tf * 16 + g * 4]) = pk;
            }

        // ---- ctx^T += Vt . P^T ----
        s16x8 pb[4][2];
        #pragma unroll
        for (int qf = 0; qf < 4; ++qf) {
            pb[qf][0] = *(const s16x8*)(&Pw[(qf * 16 + r) * 72 + g * 8]);
            pb[qf][1] = *(const s16x8*)(&Pw[(qf * 16 + r) * 72 + 32 + g * 8]);
        }
        #pragma unroll
        for (int df = 0; df < 4; ++df) {
            s16x8 va0 = *(const s16x8*)(&Vs[(df * 16 + r) * 72 + g * 8]);
            s16x8 va1 = *(const s16x8*)(&Vs[(df * 16 + r) * 72 + 32 + g * 8]);
            #pragma unroll
            for (int qf = 0; qf < 4; ++qf) {
                o[df][qf] = __builtin_amdgcn_mfma_f32_16x16x32_bf16(va0, pb[qf][0], o[df][qf], 0, 0, 0);
                o[df][qf] = __builtin_amdgcn_mfma_f32_16x16x32_bf16(va1, pb[qf][1], o[df][qf], 0, 0, 0);
            }
        }
    }

    // ---- epilogue: ctx[b*S+q][h*64+d] = o[d][q] / l[q] ----
    const int b = bh >> 3, h = bh & 7;
    #pragma unroll
    for (int qf = 0; qf < 4; ++qf) {
        const float inv = 1.0f / lrun[qf];
        const int q = q0 + qf * 16 + r;
        const size_t rowoff = (size_t)(b * SEQ + q) * DM + h * DK;
        #pragma unroll
        for (int df = 0; df < 4; ++df) {
            u16x4 pk;
            #pragma unroll
            for (int i = 0; i < 4; ++i) pk[i] = f2bf(o[df][qf][i] * inv);
            *(u16x4*)(&Ctx[rowoff + df * 16 + g * 4]) = pk;
        }
    }
}

// ---------------------------------------------------------------------------
extern "C" void kernel_launch(void* const* d_in, const int* in_sizes, int n_in,
                              void* d_out, int out_size, void* d_ws, size_t ws_size,
                              hipStream_t stream)
{
    const float* q  = (const float*)d_in[0];
    const float* k  = (const float*)d_in[1];
    const float* v  = (const float*)d_in[2];
    const float* Wq = (const float*)d_in[3];
    const float* bq = (const float*)d_in[4];
    const float* Wk = (const float*)d_in[5];
    const float* bk = (const float*)d_in[6];
    const float* Wv = (const float*)d_in[7];
    const float* bv = (const float*)d_in[8];
    const float* Wo = (const float*)d_in[9];
    const float* bo = (const float*)d_in[10];

    unsigned short* ws  = (unsigned short*)d_ws;
    unsigned short* Qw  = ws;                       // [B,H,S,64]  4.19M elems
    unsigned short* Kw  = Qw  + (size_t)MROWS * DM; // [B,H,S,64]
    unsigned short* Vtw = Kw  + (size_t)MROWS * DM; // [B,H,64,S]
    unsigned short* Ctx = Vtw + (size_t)MROWS * DM; // [B*S, 512]

    dim3 gg(MROWS / 128, DM / 128);                 // (64, 4)
    gemm_proj<false, 0><<<gg, 256, 0, stream>>>(q, Wq, bq, Qw);
    gemm_proj<false, 0><<<gg, 256, 0, stream>>>(k, Wk, bk, Kw);
    gemm_proj<false, 1><<<gg, 256, 0, stream>>>(v, Wv, bv, Vtw);
    attn_kernel<<<dim3(16, 16), 256, 0, stream>>>(Qw, Kw, Vtw, Ctx);
    gemm_proj<true, 2><<<gg, 256, 0, stream>>>(Ctx, Wo, bo, d_out);
}